// Round 2
// baseline (2952.204 us; speedup 1.0000x reference)
//
#include <hip/hip_runtime.h>

// Round 2: fix dropout to JAX *partitionable* threefry (default since jax 0.4.30).
// Pipeline (all fp32):
//   deg[n]  = #edges with dst==n                        (atomicAdd int)
//   y0      = x @ Wl0^T                                 (GEMM, plain)
//   s0      = scatter_add(y0[src] -> dst)               (atomicAdd f32)
//   h       = dropout(relu(x@Wr0^T + s0/max(deg,1) + bl0))  (GEMM + fused epilogue)
//   y1      = h @ Wl1^T                                 (GEMM, plain)
//   s1      = scatter_add(y1[src] -> d_out)             (atomicAdd f32)
//   out     = h@Wr1^T + s1/max(deg,1) + bl1             (GEMM + fused epilogue, in-place)
// Dropout mask: jax.random.bernoulli(key(42), 0.5, (N,128)) with
// threefry_partitionable=True: for flat index j, counter = (hi32(j)=0, lo32(j)=j),
// (b0,b1) = threefry2x32((0,42), counter), bits = b0^b1,
// u = bitcast(bits>>9 | 0x3f800000)-1.0, keep = u < 0.5.

#define HDIM 128

// ---------------- Threefry-2x32 (JAX partitionable mode) ----------------
__device__ __forceinline__ unsigned int tf_rotl(unsigned int x, int d) {
  return (x << d) | (x >> (32 - d));
}

__device__ __forceinline__ bool dropout_keep(unsigned int j) {
  unsigned int x0 = 0u;   // hi 32 bits of flat index (always 0: N*H < 2^32)
  unsigned int x1 = j;    // lo 32 bits of flat index
  const unsigned int ks0 = 0u;
  const unsigned int ks1 = 42u;
  const unsigned int ks2 = 0x1BD11BDAu ^ 0u ^ 42u;
  x0 += ks0; x1 += ks1;
#define TF_R(r) { x0 += x1; x1 = tf_rotl(x1, (r)); x1 ^= x0; }
  TF_R(13) TF_R(15) TF_R(26) TF_R(6)
  x0 += ks1; x1 += ks2 + 1u;
  TF_R(17) TF_R(29) TF_R(16) TF_R(24)
  x0 += ks2; x1 += ks0 + 2u;
  TF_R(13) TF_R(15) TF_R(26) TF_R(6)
  x0 += ks0; x1 += ks1 + 3u;
  TF_R(17) TF_R(29) TF_R(16) TF_R(24)
  x0 += ks1; x1 += ks2 + 4u;
  TF_R(13) TF_R(15) TF_R(26) TF_R(6)
  x0 += ks2; x1 += ks0 + 5u;
#undef TF_R
  unsigned int r = x0 ^ x1;  // 32-bit output in partitionable mode
  float u = __uint_as_float((r >> 9) | 0x3f800000u) - 1.0f;
  return u < 0.5f;
}

// ---------------- degree count ----------------
__global__ __launch_bounds__(256) void degree_k(const int* __restrict__ dst,
                                                int* __restrict__ deg, int E) {
  int t = blockIdx.x * 256 + threadIdx.x;
  if (t < E) atomicAdd(&deg[dst[t]], 1);
}

// ---------------- scatter add: S[dst] += Y[src] (row-wise, 128 floats) ----------------
// 32 threads per edge, float4 per thread.
__global__ __launch_bounds__(256) void scatter_add_k(const float* __restrict__ Y,
                                                     float* __restrict__ S,
                                                     const int* __restrict__ src,
                                                     const int* __restrict__ dst, int E) {
  int t = blockIdx.x * 256 + threadIdx.x;
  int e = t >> 5;
  if (e >= E) return;
  int c = (t & 31) * 4;
  int sn = src[e];
  int dn = dst[e];
  const float4 v = *(const float4*)&Y[(size_t)sn * HDIM + c];
  float* p = &S[(size_t)dn * HDIM + c];
  atomicAdd(p + 0, v.x);
  atomicAdd(p + 1, v.y);
  atomicAdd(p + 2, v.z);
  atomicAdd(p + 3, v.w);
}

// ---------------- GEMM: out[n][o] = sum_k A[n][k] * W[o][k]  (+ fused epilogue) ----------------
// MODE 0: plain store.
// MODE 1: v = acc + S[n][c]/max(deg,1) + bias[c]; v = relu(v); dropout(x2 or 0); store.
// MODE 2: v = acc + S[n][c]/max(deg,1) + bias[c]; store. (S may alias out.)
template <int MODE>
__global__ __launch_bounds__(256) void gemm_nt(const float* __restrict__ A,
                                               const float* __restrict__ W,
                                               float* __restrict__ out,
                                               const float* __restrict__ S,
                                               const int* __restrict__ deg,
                                               const float* __restrict__ bias,
                                               int N) {
  __shared__ float Wt[32 * 132];  // Wt[kk][o], pad 132
  __shared__ float Xt[32 * 36];   // Xt[kk][r], pad 36
  const int tid = threadIdx.x;
  const int n0 = blockIdx.x * 32;
  const int c = (tid & 31) * 4;
  const int rg = tid >> 5;

  float acc[4][4];
#pragma unroll
  for (int j = 0; j < 4; ++j)
#pragma unroll
    for (int i = 0; i < 4; ++i) acc[j][i] = 0.0f;

  for (int kc = 0; kc < 4; ++kc) {
    __syncthreads();
// stage W chunk (transposed): Wt[kk*132+o] = W[o*128 + kc*32 + kk]
#pragma unroll
    for (int i = 0; i < 16; ++i) {
      int lin = i * 256 + tid;
      int o = lin >> 5, kk = lin & 31;
      Wt[kk * 132 + o] = W[o * HDIM + kc * 32 + kk];
    }
// stage A chunk (transposed): Xt[kk*36+r] = A[(n0+r)*128 + kc*32 + kk]
#pragma unroll
    for (int i = 0; i < 4; ++i) {
      int lin = i * 256 + tid;
      int r = lin >> 5, kk = lin & 31;
      int row = n0 + r;
      if (row >= N) row = N - 1;
      Xt[kk * 36 + r] = A[(size_t)row * HDIM + kc * 32 + kk];
    }
    __syncthreads();
#pragma unroll
    for (int kk = 0; kk < 32; ++kk) {
      const float4 wv = *(const float4*)&Wt[kk * 132 + c];
      const float4 xv = *(const float4*)&Xt[kk * 36 + rg * 4];
      acc[0][0] += xv.x * wv.x; acc[0][1] += xv.x * wv.y; acc[0][2] += xv.x * wv.z; acc[0][3] += xv.x * wv.w;
      acc[1][0] += xv.y * wv.x; acc[1][1] += xv.y * wv.y; acc[1][2] += xv.y * wv.z; acc[1][3] += xv.y * wv.w;
      acc[2][0] += xv.z * wv.x; acc[2][1] += xv.z * wv.y; acc[2][2] += xv.z * wv.z; acc[2][3] += xv.z * wv.w;
      acc[3][0] += xv.w * wv.x; acc[3][1] += xv.w * wv.y; acc[3][2] += xv.w * wv.z; acc[3][3] += xv.w * wv.w;
    }
  }

// epilogue
#pragma unroll
  for (int j = 0; j < 4; ++j) {
    int n = n0 + rg * 4 + j;
    if (n >= N) continue;
    size_t base = (size_t)n * HDIM + c;
    float4 v = make_float4(acc[j][0], acc[j][1], acc[j][2], acc[j][3]);
    if (MODE != 0) {
      float d = (float)deg[n];
      if (d < 1.0f) d = 1.0f;
      float rd = 1.0f / d;
      const float4 s = *(const float4*)&S[base];
      const float4 bv = *(const float4*)&bias[c];
      v.x += s.x * rd + bv.x;
      v.y += s.y * rd + bv.y;
      v.z += s.z * rd + bv.z;
      v.w += s.w * rd + bv.w;
      if (MODE == 1) {
        // relu then dropout (keep -> x2, drop -> 0)
        v.x = v.x > 0.0f ? v.x : 0.0f;
        v.y = v.y > 0.0f ? v.y : 0.0f;
        v.z = v.z > 0.0f ? v.z : 0.0f;
        v.w = v.w > 0.0f ? v.w : 0.0f;
        unsigned int fj = (unsigned int)base;
        v.x = dropout_keep(fj + 0u) ? v.x * 2.0f : 0.0f;
        v.y = dropout_keep(fj + 1u) ? v.y * 2.0f : 0.0f;
        v.z = dropout_keep(fj + 2u) ? v.z * 2.0f : 0.0f;
        v.w = dropout_keep(fj + 3u) ? v.w * 2.0f : 0.0f;
      }
    }
    *(float4*)&out[base] = v;
  }
}

extern "C" void kernel_launch(void* const* d_in, const int* in_sizes, int n_in,
                              void* d_out, int out_size, void* d_ws, size_t ws_size,
                              hipStream_t stream) {
  const float* x   = (const float*)d_in[0];
  const int*   ei  = (const int*)d_in[1];
  const float* Wl0 = (const float*)d_in[2];
  const float* bl0 = (const float*)d_in[3];
  const float* Wr0 = (const float*)d_in[4];
  const float* Wl1 = (const float*)d_in[5];
  const float* bl1 = (const float*)d_in[6];
  const float* Wr1 = (const float*)d_in[7];
  float* out = (float*)d_out;

  const int N = in_sizes[0] / HDIM;   // 50000
  const int E = in_sizes[1] / 2;      // 800000
  const int* src = ei;
  const int* dst = ei + E;

  // workspace layout: deg (N ints) | bufA (N*128 f32) | bufB (N*128 f32)
  char* ws = (char*)d_ws;
  int* deg = (int*)ws;
  size_t degBytes = ((size_t)N * sizeof(int) + 255) & ~(size_t)255;
  float* bufA = (float*)(ws + degBytes);
  float* bufB = bufA + (size_t)N * HDIM;

  const size_t featBytes = (size_t)N * HDIM * sizeof(float);

  hipMemsetAsync(deg, 0, (size_t)N * sizeof(int), stream);
  hipMemsetAsync(bufB, 0, featBytes, stream);
  hipMemsetAsync(out, 0, featBytes, stream);

  const int GB = (N + 31) / 32;                    // 1563 blocks, 32 rows each
  const int scatterBlocks = (E * 32 + 255) / 256;  // 100000

  degree_k<<<(E + 255) / 256, 256, 0, stream>>>(dst, deg, E);

  // layer 1
  gemm_nt<0><<<GB, 256, 0, stream>>>(x, Wl0, bufA, nullptr, nullptr, nullptr, N);
  scatter_add_k<<<scatterBlocks, 256, 0, stream>>>(bufA, bufB, src, dst, E);
  gemm_nt<1><<<GB, 256, 0, stream>>>(x, Wr0, bufA, bufB, deg, bl0, N);  // h -> bufA

  // layer 2
  gemm_nt<0><<<GB, 256, 0, stream>>>(bufA, Wl1, bufB, nullptr, nullptr, nullptr, N);
  scatter_add_k<<<scatterBlocks, 256, 0, stream>>>(bufB, out, src, dst, E);
  gemm_nt<2><<<GB, 256, 0, stream>>>(bufA, Wr1, out, out, deg, bl1, N);
}

// Round 3
// 411.711 us; speedup vs baseline: 7.1706x; 7.1706x over previous
//
#include <hip/hip_runtime.h>

// Round 3: kill the f32 atomics. CSR-by-dst built per call (int atomics only),
// gather-based mean aggregation, and per-layer fused K=256 GEMM:
//   deg    = bincount(dst)                         (int atomics, 800K)
//   rowptr = exclusive_scan(deg)                   (3-kernel scan)
//   eidx   = edges bucketed by dst                 (int atomic cursor, 800K)
//   aggX   = mean_{e: dst=n} x[src[e]]             (gather, no atomics) -> bufH
//   h      = dropout(relu(aggX@Wl0^T + x@Wr0^T + bl0))   (K=256 GEMM, in-place bufH)
//   aggH   = mean h[src] per dst                   -> d_out
//   out    = aggH@Wl1^T + h@Wr1^T + bl1            (K=256 GEMM, in-place d_out)
// Dropout mask: JAX partitionable threefry (verified round 2).

#define HDIM 128

// ---------------- Threefry-2x32 (JAX partitionable mode) ----------------
__device__ __forceinline__ unsigned int tf_rotl(unsigned int x, int d) {
  return (x << d) | (x >> (32 - d));
}

__device__ __forceinline__ bool dropout_keep(unsigned int j) {
  unsigned int x0 = 0u;
  unsigned int x1 = j;
  const unsigned int ks0 = 0u;
  const unsigned int ks1 = 42u;
  const unsigned int ks2 = 0x1BD11BDAu ^ 0u ^ 42u;
  x0 += ks0; x1 += ks1;
#define TF_R(r) { x0 += x1; x1 = tf_rotl(x1, (r)); x1 ^= x0; }
  TF_R(13) TF_R(15) TF_R(26) TF_R(6)
  x0 += ks1; x1 += ks2 + 1u;
  TF_R(17) TF_R(29) TF_R(16) TF_R(24)
  x0 += ks2; x1 += ks0 + 2u;
  TF_R(13) TF_R(15) TF_R(26) TF_R(6)
  x0 += ks0; x1 += ks1 + 3u;
  TF_R(17) TF_R(29) TF_R(16) TF_R(24)
  x0 += ks1; x1 += ks2 + 4u;
  TF_R(13) TF_R(15) TF_R(26) TF_R(6)
  x0 += ks2; x1 += ks0 + 5u;
#undef TF_R
  unsigned int r = x0 ^ x1;
  float u = __uint_as_float((r >> 9) | 0x3f800000u) - 1.0f;
  return u < 0.5f;
}

// ---------------- degree count ----------------
__global__ __launch_bounds__(256) void degree_k(const int* __restrict__ dst,
                                                int* __restrict__ deg, int E) {
  int t = blockIdx.x * 256 + threadIdx.x;
  if (t < E) atomicAdd(&deg[dst[t]], 1);
}

// ---------------- exclusive scan (3 kernels) ----------------
__global__ __launch_bounds__(256) void scan1_k(const int* __restrict__ deg,
                                               int* __restrict__ excl,
                                               int* __restrict__ blockSums, int N) {
  __shared__ int tmp[256];
  int gid = blockIdx.x * 256 + threadIdx.x;
  int v = (gid < N) ? deg[gid] : 0;
  tmp[threadIdx.x] = v;
  __syncthreads();
  for (int off = 1; off < 256; off <<= 1) {
    int t = (threadIdx.x >= off) ? tmp[threadIdx.x - off] : 0;
    __syncthreads();
    tmp[threadIdx.x] += t;
    __syncthreads();
  }
  if (gid < N) excl[gid] = tmp[threadIdx.x] - v;
  if (threadIdx.x == 255) blockSums[blockIdx.x] = tmp[255];
}

__global__ __launch_bounds__(256) void scan2_k(const int* __restrict__ blockSums,
                                               int* __restrict__ blockOff, int nb) {
  __shared__ int tmp[256];
  int v = (threadIdx.x < nb) ? blockSums[threadIdx.x] : 0;
  tmp[threadIdx.x] = v;
  __syncthreads();
  for (int off = 1; off < 256; off <<= 1) {
    int t = (threadIdx.x >= off) ? tmp[threadIdx.x - off] : 0;
    __syncthreads();
    tmp[threadIdx.x] += t;
    __syncthreads();
  }
  if (threadIdx.x < nb) blockOff[threadIdx.x] = tmp[threadIdx.x] - v;
}

__global__ __launch_bounds__(256) void scan3_k(const int* __restrict__ excl,
                                               const int* __restrict__ blockOff,
                                               int* __restrict__ rowptr,
                                               int* __restrict__ cursor, int N) {
  int gid = blockIdx.x * 256 + threadIdx.x;
  if (gid < N) {
    int r = excl[gid] + blockOff[blockIdx.x];
    rowptr[gid] = r;
    cursor[gid] = r;
  }
}

// ---------------- bucket edges by dst ----------------
__global__ __launch_bounds__(256) void fill_k(const int* __restrict__ src,
                                              const int* __restrict__ dst,
                                              int* __restrict__ cursor,
                                              int* __restrict__ eidx, int E) {
  int t = blockIdx.x * 256 + threadIdx.x;
  if (t < E) {
    int p = atomicAdd(&cursor[dst[t]], 1);
    eidx[p] = src[t];
  }
}

// ---------------- gather-based mean aggregation ----------------
// One 128-thread block per dst node; thread = one column.
__global__ __launch_bounds__(128) void agg_k(const float* __restrict__ X,
                                             float* __restrict__ out,
                                             const int* __restrict__ eidx,
                                             const int* __restrict__ rowptr,
                                             const int* __restrict__ deg) {
  __shared__ int sidx[128];
  const int n = blockIdx.x;
  const int c = threadIdx.x;
  const int start = rowptr[n];
  const int d = deg[n];
  float acc = 0.0f;
  for (int base = 0; base < d; base += 128) {
    int cnt = min(128, d - base);
    if (threadIdx.x < cnt) sidx[threadIdx.x] = eidx[start + base + threadIdx.x];
    __syncthreads();
    int j = 0;
    for (; j + 4 <= cnt; j += 4) {
      int s0 = sidx[j], s1 = sidx[j + 1], s2 = sidx[j + 2], s3 = sidx[j + 3];
      float v0 = X[(size_t)s0 * HDIM + c];
      float v1 = X[(size_t)s1 * HDIM + c];
      float v2 = X[(size_t)s2 * HDIM + c];
      float v3 = X[(size_t)s3 * HDIM + c];
      acc += v0 + v1 + v2 + v3;
    }
    for (; j < cnt; ++j) acc += X[(size_t)sidx[j] * HDIM + c];
    __syncthreads();
  }
  float rd = 1.0f / fmaxf((float)d, 1.0f);
  out[(size_t)n * HDIM + c] = acc * rd;
}

// ---------------- fused K=256 GEMM: out = A0@W0^T + A1@W1^T (+ epilogue) ----------------
// MODE 1: +bias, relu, dropout (layer 1). MODE 2: +bias only (layer 2).
// In-place safe for A0==out / A1==out: each block reads only rows [n0,n0+32)
// of A0/A1 and writes exactly those rows, all reads before the epilogue store.
template <int MODE>
__global__ __launch_bounds__(256) void gemm2_nt(const float* __restrict__ A0,
                                                const float* __restrict__ W0,
                                                const float* __restrict__ A1,
                                                const float* __restrict__ W1,
                                                float* __restrict__ out,
                                                const float* __restrict__ bias,
                                                int N) {
  __shared__ float Wt[32 * 132];
  __shared__ float Xt[32 * 36];
  const int tid = threadIdx.x;
  const int n0 = blockIdx.x * 32;
  const int c = (tid & 31) * 4;
  const int rg = tid >> 5;

  float acc[4][4];
#pragma unroll
  for (int j = 0; j < 4; ++j)
#pragma unroll
    for (int i = 0; i < 4; ++i) acc[j][i] = 0.0f;

  for (int kc = 0; kc < 8; ++kc) {
    const float* Ap = (kc < 4) ? A0 : A1;
    const float* Wp = (kc < 4) ? W0 : W1;
    const int koff = (kc & 3) * 32;
    __syncthreads();
#pragma unroll
    for (int i = 0; i < 16; ++i) {
      int lin = i * 256 + tid;
      int o = lin >> 5, kk = lin & 31;
      Wt[kk * 132 + o] = Wp[o * HDIM + koff + kk];
    }
#pragma unroll
    for (int i = 0; i < 4; ++i) {
      int lin = i * 256 + tid;
      int r = lin >> 5, kk = lin & 31;
      int row = n0 + r;
      if (row >= N) row = N - 1;
      Xt[kk * 36 + r] = Ap[(size_t)row * HDIM + koff + kk];
    }
    __syncthreads();
#pragma unroll
    for (int kk = 0; kk < 32; ++kk) {
      const float4 wv = *(const float4*)&Wt[kk * 132 + c];
      const float4 xv = *(const float4*)&Xt[kk * 36 + rg * 4];
      acc[0][0] += xv.x * wv.x; acc[0][1] += xv.x * wv.y; acc[0][2] += xv.x * wv.z; acc[0][3] += xv.x * wv.w;
      acc[1][0] += xv.y * wv.x; acc[1][1] += xv.y * wv.y; acc[1][2] += xv.y * wv.z; acc[1][3] += xv.y * wv.w;
      acc[2][0] += xv.z * wv.x; acc[2][1] += xv.z * wv.y; acc[2][2] += xv.z * wv.z; acc[2][3] += xv.z * wv.w;
      acc[3][0] += xv.w * wv.x; acc[3][1] += xv.w * wv.y; acc[3][2] += xv.w * wv.z; acc[3][3] += xv.w * wv.w;
    }
  }

#pragma unroll
  for (int j = 0; j < 4; ++j) {
    int n = n0 + rg * 4 + j;
    if (n >= N) continue;
    size_t base = (size_t)n * HDIM + c;
    const float4 bv = *(const float4*)&bias[c];
    float4 v = make_float4(acc[j][0] + bv.x, acc[j][1] + bv.y,
                           acc[j][2] + bv.z, acc[j][3] + bv.w);
    if (MODE == 1) {
      v.x = v.x > 0.0f ? v.x : 0.0f;
      v.y = v.y > 0.0f ? v.y : 0.0f;
      v.z = v.z > 0.0f ? v.z : 0.0f;
      v.w = v.w > 0.0f ? v.w : 0.0f;
      unsigned int fj = (unsigned int)base;
      v.x = dropout_keep(fj + 0u) ? v.x * 2.0f : 0.0f;
      v.y = dropout_keep(fj + 1u) ? v.y * 2.0f : 0.0f;
      v.z = dropout_keep(fj + 2u) ? v.z * 2.0f : 0.0f;
      v.w = dropout_keep(fj + 3u) ? v.w * 2.0f : 0.0f;
    }
    *(float4*)&out[base] = v;
  }
}

extern "C" void kernel_launch(void* const* d_in, const int* in_sizes, int n_in,
                              void* d_out, int out_size, void* d_ws, size_t ws_size,
                              hipStream_t stream) {
  const float* x   = (const float*)d_in[0];
  const int*   ei  = (const int*)d_in[1];
  const float* Wl0 = (const float*)d_in[2];
  const float* bl0 = (const float*)d_in[3];
  const float* Wr0 = (const float*)d_in[4];
  const float* Wl1 = (const float*)d_in[5];
  const float* bl1 = (const float*)d_in[6];
  const float* Wr1 = (const float*)d_in[7];
  float* out = (float*)d_out;

  const int N = in_sizes[0] / HDIM;   // 50000
  const int E = in_sizes[1] / 2;      // 800000
  const int* src = ei;
  const int* dst = ei + E;

  // workspace: deg | excl | rowptr | cursor | blockSums | blockOff | eidx | bufH
  const int Na = (N + 63) & ~63;
  int* deg       = (int*)d_ws;
  int* excl      = deg + Na;
  int* rowptr    = excl + Na;
  int* cursor    = rowptr + Na;
  int* blockSums = cursor + Na;
  int* blockOff  = blockSums + 256;
  int* eidx      = blockOff + 256;
  size_t floatOff = (((size_t)(eidx + E) - (size_t)d_ws) + 255) & ~(size_t)255;
  float* bufH    = (float*)((char*)d_ws + floatOff);

  hipMemsetAsync(deg, 0, (size_t)N * sizeof(int), stream);

  const int nb = (N + 255) / 256;                  // 196
  const int GB = (N + 31) / 32;                    // 1563

  degree_k<<<(E + 255) / 256, 256, 0, stream>>>(dst, deg, E);
  scan1_k<<<nb, 256, 0, stream>>>(deg, excl, blockSums, N);
  scan2_k<<<1, 256, 0, stream>>>(blockSums, blockOff, nb);
  scan3_k<<<nb, 256, 0, stream>>>(excl, blockOff, rowptr, cursor, N);
  fill_k<<<(E + 255) / 256, 256, 0, stream>>>(src, dst, cursor, eidx, E);

  // layer 1: aggX -> bufH; h = dropout(relu(aggX@Wl0^T + x@Wr0^T + bl0)) in-place
  agg_k<<<N, 128, 0, stream>>>(x, bufH, eidx, rowptr, deg);
  gemm2_nt<1><<<GB, 256, 0, stream>>>(bufH, Wl0, x, Wr0, bufH, bl0, N);

  // layer 2: aggH -> d_out; out = aggH@Wl1^T + h@Wr1^T + bl1 in-place
  agg_k<<<N, 128, 0, stream>>>(bufH, out, eidx, rowptr, deg);
  gemm2_nt<2><<<GB, 256, 0, stream>>>(out, Wl1, bufH, Wr1, out, bl1, N);
}

// Round 4
// 297.681 us; speedup vs baseline: 9.9173x; 1.3831x over previous
//
#include <hip/hip_runtime.h>
#include <hip/hip_bf16.h>

// Round 4: bf16 MFMA GEMMs + bf16 gathers (threshold is bf16-level: 0.143).
//   CSR build (degree/scan/fill) unchanged.
//   Ab[n] = [aggXb (128) | xb (128)]  bf16, K=256 rows
//   gemm1: h_bf16 = dropout(relu(Ab@[Wl0|Wr0]^T + bl0)) -> A2 right half
//   A2[n] = [aggHb | hb]
//   gemm2: out_f32 = A2@[Wl1|Wr1]^T + bl1 -> d_out
// GEMM: 16x16x32 bf16 MFMA, block=256 (4 waves), 64 rows/block, wave=16 rows x 128 cols.
// W (128x256 bf16) staged in LDS (row pad 264), A-frags preloaded to regs,
// epilogue through LDS transpose for coalesced stores.

#define HDIM 128
#define KDIM 256

typedef __attribute__((ext_vector_type(8))) short bshort8;
typedef __attribute__((ext_vector_type(4))) float f32x4;

__device__ __forceinline__ ushort f2b(float f) {
  __hip_bfloat16 h = __float2bfloat16(f);  // RTNE
  return *(ushort*)&h;
}
__device__ __forceinline__ float blo(unsigned int v) { return __uint_as_float(v << 16); }
__device__ __forceinline__ float bhi(unsigned int v) { return __uint_as_float(v & 0xffff0000u); }

// ---------------- Threefry-2x32 (JAX partitionable mode, verified R2) ----------------
__device__ __forceinline__ unsigned int tf_rotl(unsigned int x, int d) {
  return (x << d) | (x >> (32 - d));
}
__device__ __forceinline__ bool dropout_keep(unsigned int j) {
  unsigned int x0 = 0u, x1 = j;
  const unsigned int ks0 = 0u, ks1 = 42u, ks2 = 0x1BD11BDAu ^ 0u ^ 42u;
  x0 += ks0; x1 += ks1;
#define TF_R(r) { x0 += x1; x1 = tf_rotl(x1, (r)); x1 ^= x0; }
  TF_R(13) TF_R(15) TF_R(26) TF_R(6)
  x0 += ks1; x1 += ks2 + 1u;
  TF_R(17) TF_R(29) TF_R(16) TF_R(24)
  x0 += ks2; x1 += ks0 + 2u;
  TF_R(13) TF_R(15) TF_R(26) TF_R(6)
  x0 += ks0; x1 += ks1 + 3u;
  TF_R(17) TF_R(29) TF_R(16) TF_R(24)
  x0 += ks1; x1 += ks2 + 4u;
  TF_R(13) TF_R(15) TF_R(26) TF_R(6)
  x0 += ks2; x1 += ks0 + 5u;
#undef TF_R
  unsigned int r = x0 ^ x1;
  float u = __uint_as_float((r >> 9) | 0x3f800000u) - 1.0f;
  return u < 0.5f;
}

// ---------------- CSR build ----------------
__global__ __launch_bounds__(256) void degree_k(const int* __restrict__ dst,
                                                int* __restrict__ deg, int E) {
  int t = blockIdx.x * 256 + threadIdx.x;
  if (t < E) atomicAdd(&deg[dst[t]], 1);
}

__global__ __launch_bounds__(256) void scan1_k(const int* __restrict__ deg,
                                               int* __restrict__ excl,
                                               int* __restrict__ blockSums, int N) {
  __shared__ int tmp[256];
  int gid = blockIdx.x * 256 + threadIdx.x;
  int v = (gid < N) ? deg[gid] : 0;
  tmp[threadIdx.x] = v;
  __syncthreads();
  for (int off = 1; off < 256; off <<= 1) {
    int t = (threadIdx.x >= off) ? tmp[threadIdx.x - off] : 0;
    __syncthreads();
    tmp[threadIdx.x] += t;
    __syncthreads();
  }
  if (gid < N) excl[gid] = tmp[threadIdx.x] - v;
  if (threadIdx.x == 255) blockSums[blockIdx.x] = tmp[255];
}

__global__ __launch_bounds__(256) void scan2_k(const int* __restrict__ blockSums,
                                               int* __restrict__ blockOff, int nb) {
  __shared__ int tmp[256];
  int v = (threadIdx.x < nb) ? blockSums[threadIdx.x] : 0;
  tmp[threadIdx.x] = v;
  __syncthreads();
  for (int off = 1; off < 256; off <<= 1) {
    int t = (threadIdx.x >= off) ? tmp[threadIdx.x - off] : 0;
    __syncthreads();
    tmp[threadIdx.x] += t;
    __syncthreads();
  }
  if (threadIdx.x < nb) blockOff[threadIdx.x] = tmp[threadIdx.x] - v;
}

__global__ __launch_bounds__(256) void scan3_k(const int* __restrict__ excl,
                                               const int* __restrict__ blockOff,
                                               int* __restrict__ rowptr,
                                               int* __restrict__ cursor, int N) {
  int gid = blockIdx.x * 256 + threadIdx.x;
  if (gid < N) {
    int r = excl[gid] + blockOff[blockIdx.x];
    rowptr[gid] = r;
    cursor[gid] = r;
  }
}

__global__ __launch_bounds__(256) void fill_k(const int* __restrict__ src,
                                              const int* __restrict__ dst,
                                              int* __restrict__ cursor,
                                              int* __restrict__ eidx, int E) {
  int t = blockIdx.x * 256 + threadIdx.x;
  if (t < E) {
    int p = atomicAdd(&cursor[dst[t]], 1);
    eidx[p] = src[t];
  }
}

// ---------------- conversions ----------------
// x f32 -> bf16 into Ab right half (row stride 256)
__global__ __launch_bounds__(256) void cvt_x_k(const float* __restrict__ x,
                                               ushort* __restrict__ Ab, int N) {
  int t = blockIdx.x * 256 + threadIdx.x;
  if (t >= N * 32) return;
  int n = t >> 5, c4 = t & 31;
  float4 v = *(const float4*)&x[(size_t)n * HDIM + c4 * 4];
  uint2 p;
  p.x = (unsigned int)f2b(v.x) | ((unsigned int)f2b(v.y) << 16);
  p.y = (unsigned int)f2b(v.z) | ((unsigned int)f2b(v.w) << 16);
  *(uint2*)&Ab[(size_t)n * KDIM + HDIM + c4 * 4] = p;
}

// weights -> combined bf16 [Wl | Wr] rows of 256
__global__ __launch_bounds__(256) void cvt_w_k(const float* __restrict__ Wl0,
                                               const float* __restrict__ Wr0,
                                               const float* __restrict__ Wl1,
                                               const float* __restrict__ Wr1,
                                               ushort* __restrict__ Wc0,
                                               ushort* __restrict__ Wc1) {
  int t = blockIdx.x * 256 + threadIdx.x;  // 16384
  int o = t >> 7, k = t & 127;
  Wc0[o * KDIM + k] = f2b(Wl0[t]);
  Wc0[o * KDIM + HDIM + k] = f2b(Wr0[t]);
  Wc1[o * KDIM + k] = f2b(Wl1[t]);
  Wc1[o * KDIM + HDIM + k] = f2b(Wr1[t]);
}

// ---------------- gather mean aggregation (bf16 in/out) ----------------
// Reads rows at Xb + s*256 + 128 (feature half), writes Ob + n*256 (agg half).
// Block = 256 threads = 4 waves, one node per wave; lane handles cols 2l,2l+1.
__global__ __launch_bounds__(256) void agg_b(const ushort* __restrict__ Xb,
                                             ushort* __restrict__ Ob,
                                             const int* __restrict__ eidx,
                                             const int* __restrict__ rowptr,
                                             const int* __restrict__ deg, int N) {
  const int lane = threadIdx.x & 63;
  const int n = blockIdx.x * 4 + (threadIdx.x >> 6);
  if (n >= N) return;
  const int start = rowptr[n];
  const int d = deg[n];
  const int co = 2 * lane;
  float a0 = 0.0f, a1 = 0.0f;
  int j = 0;
  for (; j + 4 <= d; j += 4) {
    int s0 = eidx[start + j + 0];
    int s1 = eidx[start + j + 1];
    int s2 = eidx[start + j + 2];
    int s3 = eidx[start + j + 3];
    unsigned int v0 = *(const unsigned int*)&Xb[(size_t)s0 * KDIM + HDIM + co];
    unsigned int v1 = *(const unsigned int*)&Xb[(size_t)s1 * KDIM + HDIM + co];
    unsigned int v2 = *(const unsigned int*)&Xb[(size_t)s2 * KDIM + HDIM + co];
    unsigned int v3 = *(const unsigned int*)&Xb[(size_t)s3 * KDIM + HDIM + co];
    a0 += blo(v0) + blo(v1) + blo(v2) + blo(v3);
    a1 += bhi(v0) + bhi(v1) + bhi(v2) + bhi(v3);
  }
  for (; j < d; ++j) {
    int s = eidx[start + j];
    unsigned int v = *(const unsigned int*)&Xb[(size_t)s * KDIM + HDIM + co];
    a0 += blo(v);
    a1 += bhi(v);
  }
  float rd = 1.0f / fmaxf((float)d, 1.0f);
  unsigned int p = (unsigned int)f2b(a0 * rd) | ((unsigned int)f2b(a1 * rd) << 16);
  *(unsigned int*)&Ob[(size_t)n * KDIM + co] = p;
}

// ---------------- bf16 MFMA GEMM, K=256, O=128 ----------------
// out[n][o] = sum_k A[n][k]*Wc[o][k] + bias[o]   (+ relu/dropout/bf16 in MODE 1)
// MODE 1: store bf16 to hb (row stride 256, col offset +128).
// MODE 2: store f32 to fout (row stride 128).
template <int MODE>
__global__ __launch_bounds__(256) void gemm_mfma(const ushort* __restrict__ A,
                                                 const ushort* __restrict__ Wc,
                                                 ushort* __restrict__ hb,
                                                 float* __restrict__ fout,
                                                 const float* __restrict__ bias,
                                                 int N) {
  __shared__ char smem[67584];            // 128 rows * 264 ushorts = 67584 B
  ushort* Wl = (ushort*)smem;             // K-loop: W staged, row pad 264
  float* Tl = (float*)smem;               // epilogue: 4 waves * 16 rows * 132 f32 = 33792 B
  const int tid = threadIdx.x;
  const int lane = tid & 63;
  const int wid = tid >> 6;
  const int quad = lane >> 4;
  const int l15 = lane & 15;
  const int n0 = blockIdx.x * 64;

  // stage Wc (128x256 bf16) into LDS, coalesced 16B chunks
#pragma unroll
  for (int i = 0; i < 16; ++i) {
    int q = i * 256 + tid;                // 0..4095 chunks of 8 ushorts
    int row = q >> 5, seg = q & 31;
    *(uint4*)&Wl[row * 264 + seg * 8] = *(const uint4*)&Wc[row * KDIM + seg * 8];
  }

  // preload A fragments: wave rows n0+wid*16 .. +15, all 8 k-steps
  int rowA = n0 + wid * 16 + l15;
  if (rowA >= N) rowA = N - 1;
  bshort8 af[8];
#pragma unroll
  for (int ks = 0; ks < 8; ++ks)
    af[ks] = *(const bshort8*)&A[(size_t)rowA * KDIM + ks * 32 + quad * 8];

  f32x4 acc[8];
#pragma unroll
  for (int i = 0; i < 8; ++i) acc[i] = (f32x4){0.f, 0.f, 0.f, 0.f};

  __syncthreads();

#pragma unroll
  for (int ks = 0; ks < 8; ++ks) {
#pragma unroll
    for (int os = 0; os < 8; ++os) {
      bshort8 bf = *(const bshort8*)&Wl[(os * 16 + l15) * 264 + ks * 32 + quad * 8];
      acc[os] = __builtin_amdgcn_mfma_f32_16x16x32_bf16(af[ks], bf, acc[os], 0, 0, 0);
    }
  }

  __syncthreads();  // done reading Wl; reuse LDS for transpose

  // dump accumulators: C/D layout col=lane&15, row=quad*4+reg (m89/m91)
  const int wbase = wid * (16 * 132);
#pragma unroll
  for (int os = 0; os < 8; ++os)
#pragma unroll
    for (int r = 0; r < 4; ++r)
      Tl[wbase + (quad * 4 + r) * 132 + os * 16 + l15] = acc[os][r];

  __syncthreads();

  // coalesced readback + epilogue
#pragma unroll
  for (int i = 0; i < 8; ++i) {
    int q = i * 64 + lane;       // 0..511
    int r = q >> 5;              // row within wave tile
    int c4 = q & 31;             // float4 column
    int n = n0 + wid * 16 + r;
    if (n >= N) continue;
    int c = c4 * 4;
    float4 v = *(float4*)&Tl[wbase + r * 132 + c];
    const float4 bv = *(const float4*)&bias[c];
    v.x += bv.x; v.y += bv.y; v.z += bv.z; v.w += bv.w;
    if (MODE == 1) {
      v.x = v.x > 0.0f ? v.x : 0.0f;
      v.y = v.y > 0.0f ? v.y : 0.0f;
      v.z = v.z > 0.0f ? v.z : 0.0f;
      v.w = v.w > 0.0f ? v.w : 0.0f;
      unsigned int fj = (unsigned int)n * HDIM + (unsigned int)c;
      v.x = dropout_keep(fj + 0u) ? v.x * 2.0f : 0.0f;
      v.y = dropout_keep(fj + 1u) ? v.y * 2.0f : 0.0f;
      v.z = dropout_keep(fj + 2u) ? v.z * 2.0f : 0.0f;
      v.w = dropout_keep(fj + 3u) ? v.w * 2.0f : 0.0f;
      uint2 p;
      p.x = (unsigned int)f2b(v.x) | ((unsigned int)f2b(v.y) << 16);
      p.y = (unsigned int)f2b(v.z) | ((unsigned int)f2b(v.w) << 16);
      *(uint2*)&hb[(size_t)n * KDIM + HDIM + c] = p;
    } else {
      *(float4*)&fout[(size_t)n * HDIM + c] = v;
    }
  }
}

extern "C" void kernel_launch(void* const* d_in, const int* in_sizes, int n_in,
                              void* d_out, int out_size, void* d_ws, size_t ws_size,
                              hipStream_t stream) {
  const float* x   = (const float*)d_in[0];
  const int*   ei  = (const int*)d_in[1];
  const float* Wl0 = (const float*)d_in[2];
  const float* bl0 = (const float*)d_in[3];
  const float* Wr0 = (const float*)d_in[4];
  const float* Wl1 = (const float*)d_in[5];
  const float* bl1 = (const float*)d_in[6];
  const float* Wr1 = (const float*)d_in[7];
  float* out = (float*)d_out;

  const int N = in_sizes[0] / HDIM;  // 50000
  const int E = in_sizes[1] / 2;     // 800000
  const int* src = ei;
  const int* dst = ei + E;

  // workspace: int arrays | eidx | Wc0 | Wc1 | Ab | A2
  const int Na = (N + 63) & ~63;
  int* deg       = (int*)d_ws;
  int* excl      = deg + Na;
  int* rowptr    = excl + Na;
  int* cursor    = rowptr + Na;
  int* blockSums = cursor + Na;
  int* blockOff  = blockSums + 256;
  int* eidx      = blockOff + 256;
  size_t off = (((size_t)(eidx + E) - (size_t)d_ws) + 255) & ~(size_t)255;
  ushort* Wc0 = (ushort*)((char*)d_ws + off);          // 128*256
  ushort* Wc1 = Wc0 + 128 * KDIM;
  ushort* Ab  = Wc1 + 128 * KDIM;                      // N*256
  ushort* A2  = Ab + (size_t)N * KDIM;                 // N*256

  hipMemsetAsync(deg, 0, (size_t)N * sizeof(int), stream);

  const int nb = (N + 255) / 256;       // 196
  const int eb = (E + 255) / 256;       // 3125
  const int GB = (N + 63) / 64;         // 782
  const int AB = (N + 3) / 4;           // 12500

  degree_k<<<eb, 256, 0, stream>>>(dst, deg, E);
  scan1_k<<<nb, 256, 0, stream>>>(deg, excl, blockSums, N);
  scan2_k<<<1, 256, 0, stream>>>(blockSums, blockOff, nb);
  scan3_k<<<nb, 256, 0, stream>>>(excl, blockOff, rowptr, cursor, N);
  fill_k<<<eb, 256, 0, stream>>>(src, dst, cursor, eidx, E);

  cvt_w_k<<<64, 256, 0, stream>>>(Wl0, Wr0, Wl1, Wr1, Wc0, Wc1);
  cvt_x_k<<<(N * 32 + 255) / 256, 256, 0, stream>>>(x, Ab, N);

  // layer 1
  agg_b<<<AB, 256, 0, stream>>>(Ab, Ab, eidx, rowptr, deg, N);
  gemm_mfma<1><<<GB, 256, 0, stream>>>(Ab, Wc0, A2, nullptr, bl0, N);
  // layer 2
  agg_b<<<AB, 256, 0, stream>>>(A2, A2, eidx, rowptr, deg, N);
  gemm_mfma<2><<<GB, 256, 0, stream>>>(A2, Wc1, nullptr, out, bl1, N);
}

// Round 5
// 241.775 us; speedup vs baseline: 12.2105x; 1.2312x over previous
//
#include <hip/hip_runtime.h>
#include <hip/hip_bf16.h>

// Round 5: replace atomic CSR fill (52 MB write-amplified scatter, 51 us) with a
// bucketed two-phase build: 256 buckets of 196 nodes each.
//   bhist_k: LDS histogram of dst/196            (3.2 MB read)
//   bscan_k: scan 256 bucket counts              (1 WG)
//   bin_k:   LDS-ordered scatter of packed (src<<8|dst_local) u32 pairs,
//            one global atomic per bucket per WG, coalesced run writes
//   build_k: per-bucket LDS degree hist + scan -> deg/rowptr coalesced,
//            eidx (u16) placed within a contiguous ~6 KB span (L2-local)
// Rest unchanged from R4: bf16 gather agg + 16x16x32 bf16 MFMA GEMMs with
// fused bias/relu/threefry-dropout epilogue.

#define HDIM 128
#define KDIM 256
#define NBUK 256
#define BNODE 196   // nodes per bucket (256*196 = 50176 >= 50000)
#define BCH 2048    // edges per WG in hist/bin

typedef __attribute__((ext_vector_type(8))) short bshort8;
typedef __attribute__((ext_vector_type(4))) float f32x4;

__device__ __forceinline__ ushort f2b(float f) {
  __hip_bfloat16 h = __float2bfloat16(f);  // RTNE
  return *(ushort*)&h;
}
__device__ __forceinline__ float blo(unsigned int v) { return __uint_as_float(v << 16); }
__device__ __forceinline__ float bhi(unsigned int v) { return __uint_as_float(v & 0xffff0000u); }

// ---------------- Threefry-2x32 (JAX partitionable mode, verified R2) ----------------
__device__ __forceinline__ unsigned int tf_rotl(unsigned int x, int d) {
  return (x << d) | (x >> (32 - d));
}
__device__ __forceinline__ bool dropout_keep(unsigned int j) {
  unsigned int x0 = 0u, x1 = j;
  const unsigned int ks0 = 0u, ks1 = 42u, ks2 = 0x1BD11BDAu ^ 0u ^ 42u;
  x0 += ks0; x1 += ks1;
#define TF_R(r) { x0 += x1; x1 = tf_rotl(x1, (r)); x1 ^= x0; }
  TF_R(13) TF_R(15) TF_R(26) TF_R(6)
  x0 += ks1; x1 += ks2 + 1u;
  TF_R(17) TF_R(29) TF_R(16) TF_R(24)
  x0 += ks2; x1 += ks0 + 2u;
  TF_R(13) TF_R(15) TF_R(26) TF_R(6)
  x0 += ks0; x1 += ks1 + 3u;
  TF_R(17) TF_R(29) TF_R(16) TF_R(24)
  x0 += ks1; x1 += ks2 + 4u;
  TF_R(13) TF_R(15) TF_R(26) TF_R(6)
  x0 += ks2; x1 += ks0 + 5u;
#undef TF_R
  unsigned int r = x0 ^ x1;
  float u = __uint_as_float((r >> 9) | 0x3f800000u) - 1.0f;
  return u < 0.5f;
}

// ---------------- bucketed CSR build ----------------
__global__ __launch_bounds__(256) void bhist_k(const int* __restrict__ dst,
                                               int* __restrict__ bucketCount, int E) {
  __shared__ int h[NBUK];
  h[threadIdx.x] = 0;
  __syncthreads();
  int begin = blockIdx.x * BCH;
  int n = min(BCH, E - begin);
  for (int i = threadIdx.x; i < n; i += 256) atomicAdd(&h[dst[begin + i] / BNODE], 1);
  __syncthreads();
  if (h[threadIdx.x]) atomicAdd(&bucketCount[threadIdx.x], h[threadIdx.x]);
}

__global__ __launch_bounds__(256) void bscan_k(const int* __restrict__ bucketCount,
                                               int* __restrict__ bucketStart,
                                               int* __restrict__ cursor) {
  __shared__ int tmp[NBUK];
  int v = bucketCount[threadIdx.x];
  tmp[threadIdx.x] = v;
  __syncthreads();
  for (int off = 1; off < NBUK; off <<= 1) {
    int t = (threadIdx.x >= off) ? tmp[threadIdx.x - off] : 0;
    __syncthreads();
    tmp[threadIdx.x] += t;
    __syncthreads();
  }
  int ex = tmp[threadIdx.x] - v;
  bucketStart[threadIdx.x] = ex;
  cursor[threadIdx.x] = ex;
}

__global__ __launch_bounds__(256) void bin_k(const int* __restrict__ src,
                                             const int* __restrict__ dst,
                                             int* __restrict__ cursor,
                                             unsigned int* __restrict__ pairs, int E) {
  __shared__ int hist[NBUK];
  __shared__ int lofs[NBUK];
  __shared__ int lcur[NBUK];
  __shared__ int gbase[NBUK];
  __shared__ unsigned int ordv[BCH];
  __shared__ unsigned char ordb[BCH];
  hist[threadIdx.x] = 0;
  __syncthreads();
  int begin = blockIdx.x * BCH;
  int n = min(BCH, E - begin);
  unsigned int vals[BCH / 256];
  int bks[BCH / 256];
  int cnt = 0;
  for (int i = threadIdx.x; i < n; i += 256) {
    int s = src[begin + i], d = dst[begin + i];
    int b = d / BNODE;
    int dloc = d - b * BNODE;
    vals[cnt] = ((unsigned int)s << 8) | (unsigned int)dloc;
    bks[cnt] = b;
    ++cnt;
    atomicAdd(&hist[b], 1);
  }
  __syncthreads();
  {
    int v = hist[threadIdx.x];
    lofs[threadIdx.x] = v;
    __syncthreads();
    for (int off = 1; off < NBUK; off <<= 1) {
      int t = (threadIdx.x >= off) ? lofs[threadIdx.x - off] : 0;
      __syncthreads();
      lofs[threadIdx.x] += t;
      __syncthreads();
    }
    int ex = lofs[threadIdx.x] - v;
    __syncthreads();
    lofs[threadIdx.x] = ex;
    lcur[threadIdx.x] = ex;
    gbase[threadIdx.x] = atomicAdd(&cursor[threadIdx.x], v);
  }
  __syncthreads();
  for (int k = 0; k < cnt; ++k) {
    int b = bks[k];
    int p = atomicAdd(&lcur[b], 1);
    ordv[p] = vals[k];
    ordb[p] = (unsigned char)b;
  }
  __syncthreads();
  for (int j = threadIdx.x; j < n; j += 256) {
    int b = ordb[j];
    pairs[gbase[b] + (j - lofs[b])] = ordv[j];
  }
}

__global__ __launch_bounds__(256) void build_k(const unsigned int* __restrict__ pairs,
                                               const int* __restrict__ bucketStart,
                                               const int* __restrict__ bucketCount,
                                               int* __restrict__ deg,
                                               int* __restrict__ rowptr,
                                               ushort* __restrict__ eidx, int N) {
  __shared__ int h[BNODE];
  __shared__ int lofs[BNODE];
  __shared__ int cur[BNODE];
  const int b = blockIdx.x;
  const int base = bucketStart[b];
  const int cnt = bucketCount[b];
  const int nodebase = b * BNODE;
  const int nloc = min(BNODE, N - nodebase);
  if (threadIdx.x < BNODE) h[threadIdx.x] = 0;
  __syncthreads();
  for (int i = threadIdx.x; i < cnt; i += 256) atomicAdd(&h[pairs[base + i] & 255u], 1);
  __syncthreads();
  if (threadIdx.x < BNODE) lofs[threadIdx.x] = h[threadIdx.x];
  __syncthreads();
  for (int off = 1; off < BNODE; off <<= 1) {
    int t = (threadIdx.x >= off && threadIdx.x < BNODE) ? lofs[threadIdx.x - off] : 0;
    __syncthreads();
    if (threadIdx.x < BNODE) lofs[threadIdx.x] += t;
    __syncthreads();
  }
  if (threadIdx.x < BNODE) {
    int ex = lofs[threadIdx.x] - h[threadIdx.x];
    cur[threadIdx.x] = ex;
    if (threadIdx.x < nloc) {
      deg[nodebase + threadIdx.x] = h[threadIdx.x];
      rowptr[nodebase + threadIdx.x] = base + ex;
    }
  }
  __syncthreads();
  for (int i = threadIdx.x; i < cnt; i += 256) {
    unsigned int v = pairs[base + i];
    int pos = atomicAdd(&cur[v & 255u], 1);
    eidx[base + pos] = (ushort)(v >> 8);
  }
}

// ---------------- conversions ----------------
__global__ __launch_bounds__(256) void cvt_x_k(const float* __restrict__ x,
                                               ushort* __restrict__ Ab, int N) {
  int t = blockIdx.x * 256 + threadIdx.x;
  if (t >= N * 32) return;
  int n = t >> 5, c4 = t & 31;
  float4 v = *(const float4*)&x[(size_t)n * HDIM + c4 * 4];
  uint2 p;
  p.x = (unsigned int)f2b(v.x) | ((unsigned int)f2b(v.y) << 16);
  p.y = (unsigned int)f2b(v.z) | ((unsigned int)f2b(v.w) << 16);
  *(uint2*)&Ab[(size_t)n * KDIM + HDIM + c4 * 4] = p;
}

__global__ __launch_bounds__(256) void cvt_w_k(const float* __restrict__ Wl0,
                                               const float* __restrict__ Wr0,
                                               const float* __restrict__ Wl1,
                                               const float* __restrict__ Wr1,
                                               ushort* __restrict__ Wc0,
                                               ushort* __restrict__ Wc1) {
  int t = blockIdx.x * 256 + threadIdx.x;  // 16384
  int o = t >> 7, k = t & 127;
  Wc0[o * KDIM + k] = f2b(Wl0[t]);
  Wc0[o * KDIM + HDIM + k] = f2b(Wr0[t]);
  Wc1[o * KDIM + k] = f2b(Wl1[t]);
  Wc1[o * KDIM + HDIM + k] = f2b(Wr1[t]);
}

// ---------------- gather mean aggregation (bf16 in/out) ----------------
__global__ __launch_bounds__(256) void agg_b(const ushort* __restrict__ Xb,
                                             ushort* __restrict__ Ob,
                                             const ushort* __restrict__ eidx,
                                             const int* __restrict__ rowptr,
                                             const int* __restrict__ deg, int N) {
  const int lane = threadIdx.x & 63;
  const int n = blockIdx.x * 4 + (threadIdx.x >> 6);
  if (n >= N) return;
  const int start = rowptr[n];
  const int d = deg[n];
  const int co = 2 * lane;
  float a0 = 0.0f, a1 = 0.0f;
  int j = 0;
  for (; j + 4 <= d; j += 4) {
    int s0 = eidx[start + j + 0];
    int s1 = eidx[start + j + 1];
    int s2 = eidx[start + j + 2];
    int s3 = eidx[start + j + 3];
    unsigned int v0 = *(const unsigned int*)&Xb[(size_t)s0 * KDIM + HDIM + co];
    unsigned int v1 = *(const unsigned int*)&Xb[(size_t)s1 * KDIM + HDIM + co];
    unsigned int v2 = *(const unsigned int*)&Xb[(size_t)s2 * KDIM + HDIM + co];
    unsigned int v3 = *(const unsigned int*)&Xb[(size_t)s3 * KDIM + HDIM + co];
    a0 += blo(v0) + blo(v1) + blo(v2) + blo(v3);
    a1 += bhi(v0) + bhi(v1) + bhi(v2) + bhi(v3);
  }
  for (; j < d; ++j) {
    int s = eidx[start + j];
    unsigned int v = *(const unsigned int*)&Xb[(size_t)s * KDIM + HDIM + co];
    a0 += blo(v);
    a1 += bhi(v);
  }
  float rd = 1.0f / fmaxf((float)d, 1.0f);
  unsigned int p = (unsigned int)f2b(a0 * rd) | ((unsigned int)f2b(a1 * rd) << 16);
  *(unsigned int*)&Ob[(size_t)n * KDIM + co] = p;
}

// ---------------- bf16 MFMA GEMM, K=256, O=128 ----------------
template <int MODE>
__global__ __launch_bounds__(256) void gemm_mfma(const ushort* __restrict__ A,
                                                 const ushort* __restrict__ Wc,
                                                 ushort* __restrict__ hb,
                                                 float* __restrict__ fout,
                                                 const float* __restrict__ bias,
                                                 int N) {
  __shared__ char smem[67584];            // 128 rows * 264 ushorts
  ushort* Wl = (ushort*)smem;
  float* Tl = (float*)smem;
  const int tid = threadIdx.x;
  const int lane = tid & 63;
  const int wid = tid >> 6;
  const int quad = lane >> 4;
  const int l15 = lane & 15;
  const int n0 = blockIdx.x * 64;

#pragma unroll
  for (int i = 0; i < 16; ++i) {
    int q = i * 256 + tid;
    int row = q >> 5, seg = q & 31;
    *(uint4*)&Wl[row * 264 + seg * 8] = *(const uint4*)&Wc[row * KDIM + seg * 8];
  }

  int rowA = n0 + wid * 16 + l15;
  if (rowA >= N) rowA = N - 1;
  bshort8 af[8];
#pragma unroll
  for (int ks = 0; ks < 8; ++ks)
    af[ks] = *(const bshort8*)&A[(size_t)rowA * KDIM + ks * 32 + quad * 8];

  f32x4 acc[8];
#pragma unroll
  for (int i = 0; i < 8; ++i) acc[i] = (f32x4){0.f, 0.f, 0.f, 0.f};

  __syncthreads();

#pragma unroll
  for (int ks = 0; ks < 8; ++ks) {
#pragma unroll
    for (int os = 0; os < 8; ++os) {
      bshort8 bf = *(const bshort8*)&Wl[(os * 16 + l15) * 264 + ks * 32 + quad * 8];
      acc[os] = __builtin_amdgcn_mfma_f32_16x16x32_bf16(af[ks], bf, acc[os], 0, 0, 0);
    }
  }

  __syncthreads();

  const int wbase = wid * (16 * 132);
#pragma unroll
  for (int os = 0; os < 8; ++os)
#pragma unroll
    for (int r = 0; r < 4; ++r)
      Tl[wbase + (quad * 4 + r) * 132 + os * 16 + l15] = acc[os][r];

  __syncthreads();

#pragma unroll
  for (int i = 0; i < 8; ++i) {
    int q = i * 64 + lane;
    int r = q >> 5;
    int c4 = q & 31;
    int n = n0 + wid * 16 + r;
    if (n >= N) continue;
    int c = c4 * 4;
    float4 v = *(float4*)&Tl[wbase + r * 132 + c];
    const float4 bv = *(const float4*)&bias[c];
    v.x += bv.x; v.y += bv.y; v.z += bv.z; v.w += bv.w;
    if (MODE == 1) {
      v.x = v.x > 0.0f ? v.x : 0.0f;
      v.y = v.y > 0.0f ? v.y : 0.0f;
      v.z = v.z > 0.0f ? v.z : 0.0f;
      v.w = v.w > 0.0f ? v.w : 0.0f;
      unsigned int fj = (unsigned int)n * HDIM + (unsigned int)c;
      v.x = dropout_keep(fj + 0u) ? v.x * 2.0f : 0.0f;
      v.y = dropout_keep(fj + 1u) ? v.y * 2.0f : 0.0f;
      v.z = dropout_keep(fj + 2u) ? v.z * 2.0f : 0.0f;
      v.w = dropout_keep(fj + 3u) ? v.w * 2.0f : 0.0f;
      uint2 p;
      p.x = (unsigned int)f2b(v.x) | ((unsigned int)f2b(v.y) << 16);
      p.y = (unsigned int)f2b(v.z) | ((unsigned int)f2b(v.w) << 16);
      *(uint2*)&hb[(size_t)n * KDIM + HDIM + c] = p;
    } else {
      *(float4*)&fout[(size_t)n * HDIM + c] = v;
    }
  }
}

extern "C" void kernel_launch(void* const* d_in, const int* in_sizes, int n_in,
                              void* d_out, int out_size, void* d_ws, size_t ws_size,
                              hipStream_t stream) {
  const float* x   = (const float*)d_in[0];
  const int*   ei  = (const int*)d_in[1];
  const float* Wl0 = (const float*)d_in[2];
  const float* bl0 = (const float*)d_in[3];
  const float* Wr0 = (const float*)d_in[4];
  const float* Wl1 = (const float*)d_in[5];
  const float* bl1 = (const float*)d_in[6];
  const float* Wr1 = (const float*)d_in[7];
  float* out = (float*)d_out;

  const int N = in_sizes[0] / HDIM;  // 50000
  const int E = in_sizes[1] / 2;     // 800000
  const int* src = ei;
  const int* dst = ei + E;

  // workspace: bucketCount|bucketStart|cursor (256 each) | deg | rowptr | pairs(u32 E) | eidx(u16 E) | Wc0 | Wc1 | Ab | A2
  const int Na = (N + 63) & ~63;
  int* bucketCount = (int*)d_ws;
  int* bucketStart = bucketCount + NBUK;
  int* cursor      = bucketStart + NBUK;
  int* deg         = cursor + NBUK;
  int* rowptr      = deg + Na;
  unsigned int* pairs = (unsigned int*)(rowptr + Na);
  ushort* eidx     = (ushort*)(pairs + E);
  size_t off = (((size_t)(eidx + E) - (size_t)d_ws) + 255) & ~(size_t)255;
  ushort* Wc0 = (ushort*)((char*)d_ws + off);          // 128*256
  ushort* Wc1 = Wc0 + 128 * KDIM;
  ushort* Ab  = Wc1 + 128 * KDIM;                      // N*256
  ushort* A2  = Ab + (size_t)N * KDIM;                 // N*256

  hipMemsetAsync(bucketCount, 0, NBUK * sizeof(int), stream);

  const int eb = (E + BCH - 1) / BCH;   // 391
  const int GB = (N + 63) / 64;         // 782
  const int AB = (N + 3) / 4;           // 12500

  bhist_k<<<eb, 256, 0, stream>>>(dst, bucketCount, E);
  bscan_k<<<1, 256, 0, stream>>>(bucketCount, bucketStart, cursor);
  bin_k<<<eb, 256, 0, stream>>>(src, dst, cursor, pairs, E);
  build_k<<<NBUK, 256, 0, stream>>>(pairs, bucketStart, bucketCount, deg, rowptr, eidx, N);

  cvt_w_k<<<64, 256, 0, stream>>>(Wl0, Wr0, Wl1, Wr1, Wc0, Wc1);
  cvt_x_k<<<(N * 32 + 255) / 256, 256, 0, stream>>>(x, Ab, N);

  // layer 1
  agg_b<<<AB, 256, 0, stream>>>(Ab, Ab, eidx, rowptr, deg, N);
  gemm_mfma<1><<<GB, 256, 0, stream>>>(Ab, Wc0, A2, nullptr, bl0, N);
  // layer 2
  agg_b<<<AB, 256, 0, stream>>>(A2, A2, eidx, rowptr, deg, N);
  gemm_mfma<2><<<GB, 256, 0, stream>>>(A2, Wc1, nullptr, out, bl1, N);
}

// Round 6
// 238.445 us; speedup vs baseline: 12.3810x; 1.0140x over previous
//
#include <hip/hip_runtime.h>
#include <hip/hip_bf16.h>

// Round 6: attack latency.
//   agg_b: 16 lanes/row x uint4 (16 B/lane) gather -> 4 rows per load instr,
//          unroll 4 (16 edges in flight), shfl_xor(16,32) butterfly combine.
//   gemm_mfma: W staged in two K=128 chunks -> LDS 34.8 KB -> 4 blocks/CU.
// Rest unchanged from R5 (bucketed CSR build, bf16 MFMA, fused threefry dropout).

#define HDIM 128
#define KDIM 256
#define NBUK 256
#define BNODE 196   // nodes per bucket (256*196 = 50176 >= 50000)
#define BCH 2048    // edges per WG in hist/bin

typedef __attribute__((ext_vector_type(8))) short bshort8;
typedef __attribute__((ext_vector_type(4))) float f32x4;

__device__ __forceinline__ ushort f2b(float f) {
  __hip_bfloat16 h = __float2bfloat16(f);  // RTNE
  return *(ushort*)&h;
}
__device__ __forceinline__ float blo(unsigned int v) { return __uint_as_float(v << 16); }
__device__ __forceinline__ float bhi(unsigned int v) { return __uint_as_float(v & 0xffff0000u); }
__device__ __forceinline__ unsigned int pack2(float lo, float hi) {
  return (unsigned int)f2b(lo) | ((unsigned int)f2b(hi) << 16);
}

// ---------------- Threefry-2x32 (JAX partitionable mode, verified R2) ----------------
__device__ __forceinline__ unsigned int tf_rotl(unsigned int x, int d) {
  return (x << d) | (x >> (32 - d));
}
__device__ __forceinline__ bool dropout_keep(unsigned int j) {
  unsigned int x0 = 0u, x1 = j;
  const unsigned int ks0 = 0u, ks1 = 42u, ks2 = 0x1BD11BDAu ^ 0u ^ 42u;
  x0 += ks0; x1 += ks1;
#define TF_R(r) { x0 += x1; x1 = tf_rotl(x1, (r)); x1 ^= x0; }
  TF_R(13) TF_R(15) TF_R(26) TF_R(6)
  x0 += ks1; x1 += ks2 + 1u;
  TF_R(17) TF_R(29) TF_R(16) TF_R(24)
  x0 += ks2; x1 += ks0 + 2u;
  TF_R(13) TF_R(15) TF_R(26) TF_R(6)
  x0 += ks0; x1 += ks1 + 3u;
  TF_R(17) TF_R(29) TF_R(16) TF_R(24)
  x0 += ks1; x1 += ks2 + 4u;
  TF_R(13) TF_R(15) TF_R(26) TF_R(6)
  x0 += ks2; x1 += ks0 + 5u;
#undef TF_R
  unsigned int r = x0 ^ x1;
  float u = __uint_as_float((r >> 9) | 0x3f800000u) - 1.0f;
  return u < 0.5f;
}

// ---------------- bucketed CSR build (unchanged from R5) ----------------
__global__ __launch_bounds__(256) void bhist_k(const int* __restrict__ dst,
                                               int* __restrict__ bucketCount, int E) {
  __shared__ int h[NBUK];
  h[threadIdx.x] = 0;
  __syncthreads();
  int begin = blockIdx.x * BCH;
  int n = min(BCH, E - begin);
  for (int i = threadIdx.x; i < n; i += 256) atomicAdd(&h[dst[begin + i] / BNODE], 1);
  __syncthreads();
  if (h[threadIdx.x]) atomicAdd(&bucketCount[threadIdx.x], h[threadIdx.x]);
}

__global__ __launch_bounds__(256) void bscan_k(const int* __restrict__ bucketCount,
                                               int* __restrict__ bucketStart,
                                               int* __restrict__ cursor) {
  __shared__ int tmp[NBUK];
  int v = bucketCount[threadIdx.x];
  tmp[threadIdx.x] = v;
  __syncthreads();
  for (int off = 1; off < NBUK; off <<= 1) {
    int t = (threadIdx.x >= off) ? tmp[threadIdx.x - off] : 0;
    __syncthreads();
    tmp[threadIdx.x] += t;
    __syncthreads();
  }
  int ex = tmp[threadIdx.x] - v;
  bucketStart[threadIdx.x] = ex;
  cursor[threadIdx.x] = ex;
}

__global__ __launch_bounds__(256) void bin_k(const int* __restrict__ src,
                                             const int* __restrict__ dst,
                                             int* __restrict__ cursor,
                                             unsigned int* __restrict__ pairs, int E) {
  __shared__ int hist[NBUK];
  __shared__ int lofs[NBUK];
  __shared__ int lcur[NBUK];
  __shared__ int gbase[NBUK];
  __shared__ unsigned int ordv[BCH];
  __shared__ unsigned char ordb[BCH];
  hist[threadIdx.x] = 0;
  __syncthreads();
  int begin = blockIdx.x * BCH;
  int n = min(BCH, E - begin);
  unsigned int vals[BCH / 256];
  int bks[BCH / 256];
  int cnt = 0;
  for (int i = threadIdx.x; i < n; i += 256) {
    int s = src[begin + i], d = dst[begin + i];
    int b = d / BNODE;
    int dloc = d - b * BNODE;
    vals[cnt] = ((unsigned int)s << 8) | (unsigned int)dloc;
    bks[cnt] = b;
    ++cnt;
    atomicAdd(&hist[b], 1);
  }
  __syncthreads();
  {
    int v = hist[threadIdx.x];
    lofs[threadIdx.x] = v;
    __syncthreads();
    for (int off = 1; off < NBUK; off <<= 1) {
      int t = (threadIdx.x >= off) ? lofs[threadIdx.x - off] : 0;
      __syncthreads();
      lofs[threadIdx.x] += t;
      __syncthreads();
    }
    int ex = lofs[threadIdx.x] - v;
    __syncthreads();
    lofs[threadIdx.x] = ex;
    lcur[threadIdx.x] = ex;
    gbase[threadIdx.x] = atomicAdd(&cursor[threadIdx.x], v);
  }
  __syncthreads();
  for (int k = 0; k < cnt; ++k) {
    int b = bks[k];
    int p = atomicAdd(&lcur[b], 1);
    ordv[p] = vals[k];
    ordb[p] = (unsigned char)b;
  }
  __syncthreads();
  for (int j = threadIdx.x; j < n; j += 256) {
    int b = ordb[j];
    pairs[gbase[b] + (j - lofs[b])] = ordv[j];
  }
}

__global__ __launch_bounds__(256) void build_k(const unsigned int* __restrict__ pairs,
                                               const int* __restrict__ bucketStart,
                                               const int* __restrict__ bucketCount,
                                               int* __restrict__ deg,
                                               int* __restrict__ rowptr,
                                               ushort* __restrict__ eidx, int N) {
  __shared__ int h[BNODE];
  __shared__ int lofs[BNODE];
  __shared__ int cur[BNODE];
  const int b = blockIdx.x;
  const int base = bucketStart[b];
  const int cnt = bucketCount[b];
  const int nodebase = b * BNODE;
  const int nloc = min(BNODE, N - nodebase);
  if (threadIdx.x < BNODE) h[threadIdx.x] = 0;
  __syncthreads();
  for (int i = threadIdx.x; i < cnt; i += 256) atomicAdd(&h[pairs[base + i] & 255u], 1);
  __syncthreads();
  if (threadIdx.x < BNODE) lofs[threadIdx.x] = h[threadIdx.x];
  __syncthreads();
  for (int off = 1; off < BNODE; off <<= 1) {
    int t = (threadIdx.x >= off && threadIdx.x < BNODE) ? lofs[threadIdx.x - off] : 0;
    __syncthreads();
    if (threadIdx.x < BNODE) lofs[threadIdx.x] += t;
    __syncthreads();
  }
  if (threadIdx.x < BNODE) {
    int ex = lofs[threadIdx.x] - h[threadIdx.x];
    cur[threadIdx.x] = ex;
    if (threadIdx.x < nloc) {
      deg[nodebase + threadIdx.x] = h[threadIdx.x];
      rowptr[nodebase + threadIdx.x] = base + ex;
    }
  }
  __syncthreads();
  for (int i = threadIdx.x; i < cnt; i += 256) {
    unsigned int v = pairs[base + i];
    int pos = atomicAdd(&cur[v & 255u], 1);
    eidx[base + pos] = (ushort)(v >> 8);
  }
}

// ---------------- conversions ----------------
__global__ __launch_bounds__(256) void cvt_x_k(const float* __restrict__ x,
                                               ushort* __restrict__ Ab, int N) {
  int t = blockIdx.x * 256 + threadIdx.x;
  if (t >= N * 32) return;
  int n = t >> 5, c4 = t & 31;
  float4 v = *(const float4*)&x[(size_t)n * HDIM + c4 * 4];
  uint2 p;
  p.x = pack2(v.x, v.y);
  p.y = pack2(v.z, v.w);
  *(uint2*)&Ab[(size_t)n * KDIM + HDIM + c4 * 4] = p;
}

__global__ __launch_bounds__(256) void cvt_w_k(const float* __restrict__ Wl0,
                                               const float* __restrict__ Wr0,
                                               const float* __restrict__ Wl1,
                                               const float* __restrict__ Wr1,
                                               ushort* __restrict__ Wc0,
                                               ushort* __restrict__ Wc1) {
  int t = blockIdx.x * 256 + threadIdx.x;  // 16384
  int o = t >> 7, k = t & 127;
  Wc0[o * KDIM + k] = f2b(Wl0[t]);
  Wc0[o * KDIM + HDIM + k] = f2b(Wr0[t]);
  Wc1[o * KDIM + k] = f2b(Wl1[t]);
  Wc1[o * KDIM + HDIM + k] = f2b(Wr1[t]);
}

// ---------------- gather mean aggregation (bf16 in/out) ----------------
// One wave per node. Lane layout: g = lane>>4 (edge subgroup 0..3),
// cl = lane&15 (16 B column chunk). One load instruction covers 4 rows;
// unroll 4 -> 16 edges (= avg degree) in flight. Butterfly over g at the end.
__global__ __launch_bounds__(256) void agg_b(const ushort* __restrict__ Xb,
                                             ushort* __restrict__ Ob,
                                             const ushort* __restrict__ eidx,
                                             const int* __restrict__ rowptr,
                                             const int* __restrict__ deg, int N) {
  const int lane = threadIdx.x & 63;
  const int n = blockIdx.x * 4 + (threadIdx.x >> 6);
  if (n >= N) return;
  const int start = rowptr[n];
  const int d = deg[n];
  const int g = lane >> 4;
  const int cl = lane & 15;
  float a0 = 0.f, a1 = 0.f, a2 = 0.f, a3 = 0.f, a4 = 0.f, a5 = 0.f, a6 = 0.f, a7 = 0.f;
  for (int j = 0; j < d; j += 16) {
#pragma unroll
    for (int u = 0; u < 4; ++u) {
      int e = j + u * 4 + g;
      if (e < d) {
        int s = eidx[start + e];
        uint4 v = *(const uint4*)&Xb[(size_t)s * KDIM + HDIM + cl * 8];
        a0 += blo(v.x); a1 += bhi(v.x);
        a2 += blo(v.y); a3 += bhi(v.y);
        a4 += blo(v.z); a5 += bhi(v.z);
        a6 += blo(v.w); a7 += bhi(v.w);
      }
    }
  }
  // combine the 4 edge subgroups (lanes differing in bits 4,5)
  a0 += __shfl_xor(a0, 16, 64); a0 += __shfl_xor(a0, 32, 64);
  a1 += __shfl_xor(a1, 16, 64); a1 += __shfl_xor(a1, 32, 64);
  a2 += __shfl_xor(a2, 16, 64); a2 += __shfl_xor(a2, 32, 64);
  a3 += __shfl_xor(a3, 16, 64); a3 += __shfl_xor(a3, 32, 64);
  a4 += __shfl_xor(a4, 16, 64); a4 += __shfl_xor(a4, 32, 64);
  a5 += __shfl_xor(a5, 16, 64); a5 += __shfl_xor(a5, 32, 64);
  a6 += __shfl_xor(a6, 16, 64); a6 += __shfl_xor(a6, 32, 64);
  a7 += __shfl_xor(a7, 16, 64); a7 += __shfl_xor(a7, 32, 64);
  if (g == 0) {
    float rd = 1.0f / fmaxf((float)d, 1.0f);
    uint4 p;
    p.x = pack2(a0 * rd, a1 * rd);
    p.y = pack2(a2 * rd, a3 * rd);
    p.z = pack2(a4 * rd, a5 * rd);
    p.w = pack2(a6 * rd, a7 * rd);
    *(uint4*)&Ob[(size_t)n * KDIM + cl * 8] = p;
  }
}

// ---------------- bf16 MFMA GEMM, K=256, O=128 ----------------
// W staged in two K=128 chunks: LDS 34816 B -> 4 blocks/CU (was 66 KB / 2).
template <int MODE>
__global__ __launch_bounds__(256) void gemm_mfma(const ushort* __restrict__ A,
                                                 const ushort* __restrict__ Wc,
                                                 ushort* __restrict__ hb,
                                                 float* __restrict__ fout,
                                                 const float* __restrict__ bias,
                                                 int N) {
  __shared__ char smem[34816];            // max(128*136*2, 4*16*132*4)
  ushort* Wl = (ushort*)smem;             // 128 rows x 136 ushorts (K-chunk)
  float* Tl = (float*)smem;               // epilogue transpose: 4*16*132 f32
  const int tid = threadIdx.x;
  const int lane = tid & 63;
  const int wid = tid >> 6;
  const int quad = lane >> 4;
  const int l15 = lane & 15;
  const int n0 = blockIdx.x * 64;

  // preload A fragments: wave rows n0+wid*16 .. +15, all 8 k-steps
  int rowA = n0 + wid * 16 + l15;
  if (rowA >= N) rowA = N - 1;
  bshort8 af[8];
#pragma unroll
  for (int ks = 0; ks < 8; ++ks)
    af[ks] = *(const bshort8*)&A[(size_t)rowA * KDIM + ks * 32 + quad * 8];

  f32x4 acc[8];
#pragma unroll
  for (int i = 0; i < 8; ++i) acc[i] = (f32x4){0.f, 0.f, 0.f, 0.f};

#pragma unroll
  for (int half = 0; half < 2; ++half) {
    __syncthreads();
    // stage W[:, half*128 : half*128+128]: 2048 uint4 chunks
#pragma unroll
    for (int i = 0; i < 8; ++i) {
      int q = i * 256 + tid;
      int row = q >> 4, seg = q & 15;
      *(uint4*)&Wl[row * 136 + seg * 8] = *(const uint4*)&Wc[row * KDIM + half * HDIM + seg * 8];
    }
    __syncthreads();
#pragma unroll
    for (int ks = 0; ks < 4; ++ks) {
#pragma unroll
      for (int os = 0; os < 8; ++os) {
        bshort8 bf = *(const bshort8*)&Wl[(os * 16 + l15) * 136 + ks * 32 + quad * 8];
        acc[os] = __builtin_amdgcn_mfma_f32_16x16x32_bf16(af[half * 4 + ks], bf, acc[os], 0, 0, 0);
      }
    }
  }

  __syncthreads();  // done reading Wl; reuse LDS for transpose

  const int wbase = wid * (16 * 132);
#pragma unroll
  for (int os = 0; os < 8; ++os)
#pragma unroll
    for (int r = 0; r < 4; ++r)
      Tl[wbase + (quad * 4 + r) * 132 + os * 16 + l15] = acc[os][r];

  __syncthreads();

#pragma unroll
  for (int i = 0; i < 8; ++i) {
    int q = i * 64 + lane;
    int r = q >> 5;
    int c4 = q & 31;
    int n = n0 + wid * 16 + r;
    if (n >= N) continue;
    int c = c4 * 4;
    float4 v = *(float4*)&Tl[wbase + r * 132 + c];
    const float4 bv = *(const float4*)&bias[c];
    v.x += bv.x; v.y += bv.y; v.z += bv.z; v.w += bv.w;
    if (MODE == 1) {
      v.x = v.x > 0.0f ? v.x : 0.0f;
      v.y = v.y > 0.0f ? v.y : 0.0f;
      v.z = v.z > 0.0f ? v.z : 0.0f;
      v.w = v.w > 0.0f ? v.w : 0.0f;
      unsigned int fj = (unsigned int)n * HDIM + (unsigned int)c;
      v.x = dropout_keep(fj + 0u) ? v.x * 2.0f : 0.0f;
      v.y = dropout_keep(fj + 1u) ? v.y * 2.0f : 0.0f;
      v.z = dropout_keep(fj + 2u) ? v.z * 2.0f : 0.0f;
      v.w = dropout_keep(fj + 3u) ? v.w * 2.0f : 0.0f;
      uint2 p;
      p.x = pack2(v.x, v.y);
      p.y = pack2(v.z, v.w);
      *(uint2*)&hb[(size_t)n * KDIM + HDIM + c] = p;
    } else {
      *(float4*)&fout[(size_t)n * HDIM + c] = v;
    }
  }
}

extern "C" void kernel_launch(void* const* d_in, const int* in_sizes, int n_in,
                              void* d_out, int out_size, void* d_ws, size_t ws_size,
                              hipStream_t stream) {
  const float* x   = (const float*)d_in[0];
  const int*   ei  = (const int*)d_in[1];
  const float* Wl0 = (const float*)d_in[2];
  const float* bl0 = (const float*)d_in[3];
  const float* Wr0 = (const float*)d_in[4];
  const float* Wl1 = (const float*)d_in[5];
  const float* bl1 = (const float*)d_in[6];
  const float* Wr1 = (const float*)d_in[7];
  float* out = (float*)d_out;

  const int N = in_sizes[0] / HDIM;  // 50000
  const int E = in_sizes[1] / 2;     // 800000
  const int* src = ei;
  const int* dst = ei + E;

  // workspace: bucketCount|bucketStart|cursor (256 each) | deg | rowptr | pairs(u32 E) | eidx(u16 E) | Wc0 | Wc1 | Ab | A2
  const int Na = (N + 63) & ~63;
  int* bucketCount = (int*)d_ws;
  int* bucketStart = bucketCount + NBUK;
  int* cursor      = bucketStart + NBUK;
  int* deg         = cursor + NBUK;
  int* rowptr      = deg + Na;
  unsigned int* pairs = (unsigned int*)(rowptr + Na);
  ushort* eidx     = (ushort*)(pairs + E);
  size_t off = (((size_t)(eidx + E) - (size_t)d_ws) + 255) & ~(size_t)255;
  ushort* Wc0 = (ushort*)((char*)d_ws + off);          // 128*256
  ushort* Wc1 = Wc0 + 128 * KDIM;
  ushort* Ab  = Wc1 + 128 * KDIM;                      // N*256
  ushort* A2  = Ab + (size_t)N * KDIM;                 // N*256

  hipMemsetAsync(bucketCount, 0, NBUK * sizeof(int), stream);

  const int eb = (E + BCH - 1) / BCH;   // 391
  const int GB = (N + 63) / 64;         // 782
  const int AB = (N + 3) / 4;           // 12500

  bhist_k<<<eb, 256, 0, stream>>>(dst, bucketCount, E);
  bscan_k<<<1, 256, 0, stream>>>(bucketCount, bucketStart, cursor);
  bin_k<<<eb, 256, 0, stream>>>(src, dst, cursor, pairs, E);
  build_k<<<NBUK, 256, 0, stream>>>(pairs, bucketStart, bucketCount, deg, rowptr, eidx, N);

  cvt_w_k<<<64, 256, 0, stream>>>(Wl0, Wr0, Wl1, Wr1, Wc0, Wc1);
  cvt_x_k<<<(N * 32 + 255) / 256, 256, 0, stream>>>(x, Ab, N);

  // layer 1
  agg_b<<<AB, 256, 0, stream>>>(Ab, Ab, eidx, rowptr, deg, N);
  gemm_mfma<1><<<GB, 256, 0, stream>>>(Ab, Wc0, A2, nullptr, bl0, N);
  // layer 2
  agg_b<<<AB, 256, 0, stream>>>(A2, A2, eidx, rowptr, deg, N);
  gemm_mfma<2><<<GB, 256, 0, stream>>>(A2, Wc1, nullptr, out, bl1, N);
}